// Round 6
// baseline (695.202 us; speedup 1.0000x reference)
//
#include <hip/hip_runtime.h>
#include <hip/hip_bf16.h>

using u16 = unsigned short;
using u32 = unsigned int;

#define NN 100000
#define NE 1000000
#define NBKT 196   // col/row buckets: (NN-1)>>9 = 195
#define NBLK 489   // ceil(NE/2048)

typedef __attribute__((ext_vector_type(8))) short bfrag;
typedef __attribute__((ext_vector_type(4))) float ffrag;

#define BF16ONE2 0x3F803F80u

__device__ __forceinline__ float bf2f(u16 u) { return __uint_as_float(((u32)u) << 16); }
__device__ __forceinline__ u16 f2bf(float f) {
  u32 x = __float_as_uint(f);
  return (u16)((x + 0x7fffu + ((x >> 16) & 1u)) >> 16);
}
__device__ __forceinline__ float rdv(const void* p, long i, int f) {
  return f ? bf2f(((const u16*)p)[i]) : ((const float*)p)[i];
}
__device__ __forceinline__ void acc8(float* a, uint4 v, float w) {
  a[0] = fmaf(w, __uint_as_float(v.x << 16), a[0]);
  a[1] = fmaf(w, __uint_as_float(v.x & 0xffff0000u), a[1]);
  a[2] = fmaf(w, __uint_as_float(v.y << 16), a[2]);
  a[3] = fmaf(w, __uint_as_float(v.y & 0xffff0000u), a[3]);
  a[4] = fmaf(w, __uint_as_float(v.z << 16), a[4]);
  a[5] = fmaf(w, __uint_as_float(v.z & 0xffff0000u), a[5]);
  a[6] = fmaf(w, __uint_as_float(v.w << 16), a[6]);
  a[7] = fmaf(w, __uint_as_float(v.w & 0xffff0000u), a[7]);
}
// BN+ReLU applied to source value before weighted accumulate
__device__ __forceinline__ void acc8bn(float* a, uint4 v, float w, const float* A,
                                       const float* Bb) {
  float x;
  x = __uint_as_float(v.x << 16);
  a[0] = fmaf(w, fmaxf(fmaf(A[0], x, Bb[0]), 0.f), a[0]);
  x = __uint_as_float(v.x & 0xffff0000u);
  a[1] = fmaf(w, fmaxf(fmaf(A[1], x, Bb[1]), 0.f), a[1]);
  x = __uint_as_float(v.y << 16);
  a[2] = fmaf(w, fmaxf(fmaf(A[2], x, Bb[2]), 0.f), a[2]);
  x = __uint_as_float(v.y & 0xffff0000u);
  a[3] = fmaf(w, fmaxf(fmaf(A[3], x, Bb[3]), 0.f), a[3]);
  x = __uint_as_float(v.z << 16);
  a[4] = fmaf(w, fmaxf(fmaf(A[4], x, Bb[4]), 0.f), a[4]);
  x = __uint_as_float(v.z & 0xffff0000u);
  a[5] = fmaf(w, fmaxf(fmaf(A[5], x, Bb[5]), 0.f), a[5]);
  x = __uint_as_float(v.w << 16);
  a[6] = fmaf(w, fmaxf(fmaf(A[6], x, Bb[6]), 0.f), a[6]);
  x = __uint_as_float(v.w & 0xffff0000u);
  a[7] = fmaf(w, fmaxf(fmaf(A[7], x, Bb[7]), 0.f), a[7]);
}

// wq (u16) element offsets
#define OWXT 0
#define OWPRE 16384
#define OWD1 32768
#define OW11 49152
#define OV21 65536
#define OWD2 81920
#define OW12 98304
#define OV22 114688
#define OWPOST 131072
#define OWET 147456

#define ASTRIDE 136
#define ESTRIDE 132

struct PrepArgs { const void* in[16]; };

__global__ void k_prep(PrepArgs a, const u32* __restrict__ gp, u16* __restrict__ wq,
                       float* __restrict__ wf) {
  int t = blockIdx.x * 256 + threadIdx.x;
  int f = (gp[0] == BF16ONE2) ? 1 : 0;
  if (t < 16384) {
    int o = t >> 7, k = t & 127;
    int ko = k * 128 + o;
    int ok = o * 128 + k;
    wq[OWXT + ok] = f2bf(rdv(a.in[0], ko, f));
    wq[OWPRE + ok] = f2bf(rdv(a.in[2], ko, f));
    float c0 = rdv(a.in[6], ko, f);
    float c1 = rdv(a.in[6], 16384 + ko, f);
    float c2 = rdv(a.in[6], 32768 + ko, f);
    wq[OWD1 + ok] = f2bf(c0 - c2);
    wq[OW11 + ok] = f2bf(c1);
    wq[OV21 + ok] = f2bf(2.f * c2);
    float d0 = rdv(a.in[8], ko, f);
    float d1 = rdv(a.in[8], 16384 + ko, f);
    float d2 = rdv(a.in[8], 32768 + ko, f);
    wq[OWD2 + ok] = f2bf(d0 - d2);
    wq[OW12 + ok] = f2bf(d1);
    wq[OV22 + ok] = f2bf(2.f * d2);
    wq[OWPOST + ok] = f2bf(rdv(a.in[10], ko, f));
  }
  if (t < 4096) {
    int o = t >> 5, k = t & 31;
    wq[OWET + o * 32 + k] = (k < 16) ? f2bf(rdv(a.in[0], (long)(128 + k) * 128 + o, f)) : (u16)0;
  }
  if (t < 1281) {
    int s = t >> 7, j = t & 127;
    const int map[11] = {1, 3, 4, 5, 7, 9, 11, 12, 13, 14, 15};
    wf[t] = rdv(a.in[map[s]], j, f);
  }
}

// ======== CSR build via LDS two-level counting sort (zero global atomics) ========

__global__ void k_cnt(const int* __restrict__ ei, int* __restrict__ bcnt,
                      int* __restrict__ rbcnt) {
  __shared__ int hc[NBKT], hr[NBKT];
  int t = threadIdx.x, blk = blockIdx.x;
  for (int i = t; i < NBKT; i += 256) { hc[i] = 0; hr[i] = 0; }
  __syncthreads();
  long base = (long)blk * 2048;
#pragma unroll
  for (int i = 0; i < 8; i++) {
    long e = base + i * 256 + t;
    if (e < NE) {
      atomicAdd(&hc[ei[NE + e] >> 9], 1);
      atomicAdd(&hr[ei[e] >> 9], 1);
    }
  }
  __syncthreads();
  for (int i = t; i < NBKT; i += 256) {
    bcnt[i * NBLK + blk] = hc[i];
    rbcnt[i * NBLK + blk] = hr[i];
  }
}

__global__ void k_bscan(int* __restrict__ bcnt, int* __restrict__ rbcnt,
                        int* __restrict__ btot) {
  __shared__ int ss[256];
  int j = blockIdx.x, t = threadIdx.x;
  int* arr = ((j < NBKT) ? bcnt : rbcnt) + (j % NBKT) * NBLK;
  int a = (2 * t < NBLK) ? arr[2 * t] : 0;
  int b = (2 * t + 1 < NBLK) ? arr[2 * t + 1] : 0;
  ss[t] = a + b;
  __syncthreads();
  for (int st = 1; st < 256; st <<= 1) {
    int x = (t >= st) ? ss[t - st] : 0;
    __syncthreads();
    ss[t] += x;
    __syncthreads();
  }
  int base = ss[t] - a - b;
  if (2 * t < NBLK) arr[2 * t] = base;
  if (2 * t + 1 < NBLK) arr[2 * t + 1] = base + a;
  if (t == 255) btot[j] = ss[255];
}

__global__ void k_bbase(const int* __restrict__ btot, int* __restrict__ bbase,
                        int* __restrict__ rbbase, int* __restrict__ off) {
  __shared__ int ss[256];
  int t = threadIdx.x;
  int v = (t < NBKT) ? btot[t] : 0;
  ss[t] = v;
  __syncthreads();
  for (int st = 1; st < 256; st <<= 1) {
    int x = (t >= st) ? ss[t - st] : 0;
    __syncthreads();
    ss[t] += x;
    __syncthreads();
  }
  if (t < NBKT) bbase[t] = ss[t] - v;
  if (t == NBKT - 1) bbase[NBKT] = ss[t];
  __syncthreads();
  int v2 = (t < NBKT) ? btot[NBKT + t] : 0;
  ss[t] = v2;
  __syncthreads();
  for (int st = 1; st < 256; st <<= 1) {
    int x = (t >= st) ? ss[t - st] : 0;
    __syncthreads();
    ss[t] += x;
    __syncthreads();
  }
  if (t < NBKT) rbbase[t] = ss[t] - v2;
  if (t == NBKT - 1) rbbase[NBKT] = ss[t];
  if (t == 0) off[NN] = NE;
}

// coarse scatter: sle=(low9<<20)|eid20, srow=row, srl=row&511
__global__ void k_scat(const int* __restrict__ ei, const int* __restrict__ bofs,
                       const int* __restrict__ rbofs, const int* __restrict__ bbase,
                       const int* __restrict__ rbbase, u32* __restrict__ sle,
                       u32* __restrict__ srow, u16* __restrict__ srl) {
  __shared__ int cc[NBKT], cr[NBKT], cbase[NBKT], rbase[NBKT];
  int t = threadIdx.x, blk = blockIdx.x;
  for (int i = t; i < NBKT; i += 256) {
    cc[i] = 0;
    cr[i] = 0;
    cbase[i] = bbase[i] + bofs[i * NBLK + blk];
    rbase[i] = rbbase[i] + rbofs[i * NBLK + blk];
  }
  __syncthreads();
  long base = (long)blk * 2048;
#pragma unroll
  for (int i = 0; i < 8; i++) {
    long e = base + i * 256 + t;
    if (e < NE) {
      int c = ei[NE + e], r = ei[e];
      int k1 = atomicAdd(&cc[c >> 9], 1);
      int d1 = cbase[c >> 9] + k1;
      sle[d1] = ((u32)(c & 511) << 20) | (u32)e;
      srow[d1] = (u32)r;
      int k2 = atomicAdd(&cr[r >> 9], 1);
      int d2 = rbase[r >> 9] + k2;
      srl[d2] = (u16)(r & 511);
    }
  }
}

// fine counting sort: writes off[], crow[] (final CSR), pose[eid]=pos
__global__ void k_fine(const u32* __restrict__ sle, const u32* __restrict__ srow,
                       const int* __restrict__ bbase, int* __restrict__ off,
                       int* __restrict__ crow, int* __restrict__ pose) {
  __shared__ u32 hist[512];
  __shared__ u32 ss[256];
  int t = threadIdx.x, b = blockIdx.x;
  hist[t] = 0;
  hist[t + 256] = 0;
  __syncthreads();
  int lo = bbase[b], hi = bbase[b + 1];
  for (int p = lo + t; p < hi; p += 256) atomicAdd(&hist[sle[p] >> 20], 1);
  __syncthreads();
  u32 a = hist[2 * t], bb = hist[2 * t + 1];
  ss[t] = a + bb;
  __syncthreads();
  for (int st = 1; st < 256; st <<= 1) {
    u32 x = (t >= st) ? ss[t - st] : 0;
    __syncthreads();
    ss[t] += x;
    __syncthreads();
  }
  u32 base = ss[t] - a - bb;
  u32 c0 = (u32)lo + base, c1 = (u32)lo + base + a;
  hist[2 * t] = c0;
  hist[2 * t + 1] = c1;
  int col0 = b * 512 + 2 * t, col1 = col0 + 1;
  if (col0 < NN) off[col0] = (int)c0;
  if (col1 < NN) off[col1] = (int)c1;
  __syncthreads();
  for (int p = lo + t; p < hi; p += 256) {
    u32 v = sle[p];
    u32 pos = atomicAdd(&hist[v >> 20], 1);
    crow[pos] = (int)srow[p];
    pose[v & 0xFFFFFu] = (int)pos;
  }
}

// out-degree from row-staged low bits
__global__ void k_deg(const u16* __restrict__ srl, const int* __restrict__ rbbase,
                      int* __restrict__ deg) {
  __shared__ int hist[512];
  int t = threadIdx.x, b = blockIdx.x;
  hist[t] = 0;
  hist[t + 256] = 0;
  __syncthreads();
  int lo = rbbase[b], hi = rbbase[b + 1];
  for (int p = lo + t; p < hi; p += 256) atomicAdd(&hist[srl[p]], 1);
  __syncthreads();
  int n0 = b * 512 + t, n1 = n0 + 256;
  if (n0 < NN) deg[n0] = hist[t];
  if (n1 < NN) deg[n1] = hist[t + 256];
}

// ---- eattr -> CSR-order (coalesced read in edge order, scatter-write via pose) ----
__global__ void k_escat(const void* __restrict__ eattr, const u32* __restrict__ gp,
                        const int* __restrict__ pose, u16* __restrict__ eac) {
  long t = (long)blockIdx.x * 256 + threadIdx.x;
  long e0 = t * 4;
  if (e0 >= NE) return;
  int n = (e0 + 4 <= NE) ? 4 : (int)(NE - e0);
  if (gp[0] == BF16ONE2) {
    const uint4* src = (const uint4*)((const u16*)eattr + e0 * 16);
    for (int i = 0; i < n; i++) {
      long pos = pose[e0 + i];
      uint4* d = (uint4*)(eac + pos * 16);
      d[0] = src[i * 2];
      d[1] = src[i * 2 + 1];
    }
  } else {
    const float* src = (const float*)eattr + e0 * 16;
    for (int i = 0; i < n; i++) {
      long pos = pose[e0 + i];
      uint4* d = (uint4*)(eac + pos * 16);
      uint4 o0, o1;
      const float* s = src + i * 16;
      o0.x = (u32)f2bf(s[0]) | ((u32)f2bf(s[1]) << 16);
      o0.y = (u32)f2bf(s[2]) | ((u32)f2bf(s[3]) << 16);
      o0.z = (u32)f2bf(s[4]) | ((u32)f2bf(s[5]) << 16);
      o0.w = (u32)f2bf(s[6]) | ((u32)f2bf(s[7]) << 16);
      o1.x = (u32)f2bf(s[8]) | ((u32)f2bf(s[9]) << 16);
      o1.y = (u32)f2bf(s[10]) | ((u32)f2bf(s[11]) << 16);
      o1.z = (u32)f2bf(s[12]) | ((u32)f2bf(s[13]) << 16);
      o1.w = (u32)f2bf(s[14]) | ((u32)f2bf(s[15]) << 16);
      d[0] = o0;
      d[1] = o1;
    }
  }
}

// ------------- standalone SpMM (weighted): dst = L(BN?(src)) -------------
template <int BN>
__global__ __launch_bounds__(256) void k_spmm(const u16* __restrict__ src,
                                              u16* __restrict__ dst,
                                              const int* __restrict__ off,
                                              const int* __restrict__ crow,
                                              const float* __restrict__ cnorm,
                                              const float* __restrict__ ab) {
  int t = threadIdx.x;
  int node = blockIdx.x * 8 + (t >> 5);
  if (node >= NN) return;
  int l = t & 31;
  int half = l >> 4;
  int c = (l & 15) * 8;
  float A[8], Bb[8];
  if (BN) {
#pragma unroll
    for (int j = 0; j < 8; j++) {
      A[j] = ab[c + j];
      Bb[j] = ab[128 + c + j];
    }
  }
  int p0 = off[node], p1 = off[node + 1];
  float a[8];
#pragma unroll
  for (int j = 0; j < 8; j++) a[j] = 0.f;
  const u16* sp = src + c;
  for (int p = p0 + half; p < p1; p += 8) {
    int rr[4];
    float w[4];
#pragma unroll
    for (int u = 0; u < 4; u++) {
      int q = p + u * 2;
      int qc = q < p1 ? q : p1 - 1;
      rr[u] = crow[qc];
      w[u] = (q < p1) ? cnorm[qc] : 0.f;
    }
#pragma unroll
    for (int u = 0; u < 4; u++) {
      uint4 v = *(const uint4*)(sp + (long)rr[u] * 128);
      if (BN) acc8bn(a, v, w[u], A, Bb);
      else acc8(a, v, w[u]);
    }
  }
#pragma unroll
  for (int j = 0; j < 8; j++) a[j] += __shfl_xor(a[j], 16);
  if (half) return;
  uint4 o;
  o.x = (u32)f2bf(a[0]) | ((u32)f2bf(a[1]) << 16);
  o.y = (u32)f2bf(a[2]) | ((u32)f2bf(a[3]) << 16);
  o.z = (u32)f2bf(a[4]) | ((u32)f2bf(a[5]) << 16);
  o.w = (u32)f2bf(a[6]) | ((u32)f2bf(a[7]) << 16);
  *(uint4*)(dst + (long)node * 128 + c) = o;
}

// ------------- gather L(src) (or segsum) for 64 rows into LDS; masked 8-batch -------------
template <int WEIGHTED>
__device__ __forceinline__ void gather_lds(u16* sA, const u16* __restrict__ src,
                                           const int* __restrict__ off,
                                           const int* __restrict__ crow,
                                           const float* __restrict__ cnorm, int r0) {
  int tid = threadIdx.x;
  int grp = tid >> 4;      // 16 groups of 16 lanes
  int c = (tid & 15) * 8;  // 8 cols per lane
  const u16* sp = src + c;
#pragma unroll
  for (int i = 0; i < 4; i++) {
    int nl = grp * 4 + i;
    int node = r0 + nl;
    float a[8];
#pragma unroll
    for (int j = 0; j < 8; j++) a[j] = 0.f;
    if (node < NN) {
      int p0 = off[node], p1 = off[node + 1];
      for (int p = p0; p < p1; p += 8) {
        int rr[8];
        float w[8];
#pragma unroll
        for (int u = 0; u < 8; u++) {
          int q = p + u;
          int qc = q < p1 ? q : p1 - 1;
          rr[u] = crow[qc];
          w[u] = (q < p1) ? (WEIGHTED ? cnorm[qc] : 1.f) : 0.f;
        }
#pragma unroll
        for (int u = 0; u < 8; u++)
          acc8(a, *(const uint4*)(sp + (long)rr[u] * 128), w[u]);
      }
    }
    uint4 o;
    o.x = (u32)f2bf(a[0]) | ((u32)f2bf(a[1]) << 16);
    o.y = (u32)f2bf(a[2]) | ((u32)f2bf(a[3]) << 16);
    o.z = (u32)f2bf(a[4]) | ((u32)f2bf(a[5]) << 16);
    o.w = (u32)f2bf(a[6]) | ((u32)f2bf(a[7]) << 16);
    *(uint4*)(sA + nl * ASTRIDE + c) = o;
  }
}

// ------------- edge_attr segsum ([N,16], coalesced CSR-ordered) + cnorm -------------
__global__ __launch_bounds__(256) void k_asum(const u16* __restrict__ eac,
                                              u16* __restrict__ asum,
                                              const int* __restrict__ off,
                                              const int* __restrict__ crow,
                                              const int* __restrict__ deg,
                                              float* __restrict__ cnorm) {
  int t = blockIdx.x * 256 + threadIdx.x;
  int node = t >> 4;
  if (node >= NN) return;
  int j = t & 15;
  int p0 = off[node], p1 = off[node + 1];
  int dn = deg[node];
  float ndis = dn > 0 ? -rsqrtf((float)dn) : 0.f;
  for (int p = p0 + j; p < p1; p += 16)
    cnorm[p] = ndis * rsqrtf((float)deg[crow[p]]);  // deg[crow] >= 1 by construction
  float a0 = 0.f, a1 = 0.f, a2 = 0.f, a3 = 0.f;
  int p = p0;
  for (; p + 4 <= p1; p += 4) {
    a0 += bf2f(eac[(long)p * 16 + j]);
    a1 += bf2f(eac[(long)(p + 1) * 16 + j]);
    a2 += bf2f(eac[(long)(p + 2) * 16 + j]);
    a3 += bf2f(eac[(long)(p + 3) * 16 + j]);
  }
  for (; p < p1; p++) a0 += bf2f(eac[(long)p * 16 + j]);
  asum[(long)node * 16 + j] = f2bf((a0 + a1) + (a2 + a3));
}

// ------------- plain MFMA GEMM (ROWS=128): out = A0@W0T^T + bias (+partials) -------------
struct MArgs {
  const void* A0; const u16* W0T; int a0raw;
  const float* bias;
  u16* out;
  const u32* gp;
  float* part;
};

__global__ __launch_bounds__(256) void k_mgemm(MArgs m) {
  constexpr int ROWS = 128, RT = 8, TPR = 2, SEGW = 64;
  __shared__ __align__(16) u16 sA[ROWS * ASTRIDE];
  int tid = threadIdx.x;
  int wv = tid >> 6, lane = tid & 63;
  int col16 = lane & 15, quad = lane >> 4;
  int r0 = blockIdx.x * ROWS;

  ffrag acc[RT * 2];
#pragma unroll
  for (int i = 0; i < RT * 2; i++)
#pragma unroll
    for (int g = 0; g < 4; g++) acc[i][g] = 0.f;

  {
    int row = tid / TPR, seg = tid % TPR;
    int ra = r0 + row;
    if (ra >= NN) ra = NN - 1;
    bool f32a = m.a0raw && (m.gp[0] != BF16ONE2);
    if (f32a) {
      const float* gs = (const float*)m.A0 + (long)ra * 128 + seg * SEGW;
      u32* lp = (u32*)(sA + row * ASTRIDE + seg * SEGW);
#pragma unroll
      for (int e = 0; e < SEGW / 8; e++) {
        float4 v0 = *(const float4*)(gs + e * 8);
        float4 v1 = *(const float4*)(gs + e * 8 + 4);
        lp[e * 4 + 0] = (u32)f2bf(v0.x) | ((u32)f2bf(v0.y) << 16);
        lp[e * 4 + 1] = (u32)f2bf(v0.z) | ((u32)f2bf(v0.w) << 16);
        lp[e * 4 + 2] = (u32)f2bf(v1.x) | ((u32)f2bf(v1.y) << 16);
        lp[e * 4 + 3] = (u32)f2bf(v1.z) | ((u32)f2bf(v1.w) << 16);
      }
    } else {
      const u16* gs = (const u16*)m.A0 + (long)ra * 128 + seg * SEGW;
      uint4* lp = (uint4*)(sA + row * ASTRIDE + seg * SEGW);
#pragma unroll
      for (int e = 0; e < SEGW / 8; e++) lp[e] = *(const uint4*)(gs + e * 8);
    }
  }
  bfrag b0[2][4];
#pragma unroll
  for (int c = 0; c < 2; c++)
#pragma unroll
    for (int kb = 0; kb < 4; kb++)
      b0[c][kb] = *(const bfrag*)(m.W0T + (long)(wv * 32 + c * 16 + col16) * 128 + kb * 32 + quad * 8);
  __syncthreads();
#pragma unroll
  for (int kb = 0; kb < 4; kb++)
#pragma unroll
    for (int rt = 0; rt < RT; rt++) {
      bfrag af = *(const bfrag*)(sA + (rt * 16 + col16) * ASTRIDE + kb * 32 + quad * 8);
      acc[rt * 2 + 0] = __builtin_amdgcn_mfma_f32_16x16x32_bf16(af, b0[0][kb], acc[rt * 2 + 0], 0, 0, 0);
      acc[rt * 2 + 1] = __builtin_amdgcn_mfma_f32_16x16x32_bf16(af, b0[1][kb], acc[rt * 2 + 1], 0, 0, 0);
    }
  __syncthreads();
#pragma unroll
  for (int rt = 0; rt < RT; rt++)
#pragma unroll
    for (int c = 0; c < 2; c++) {
      int col = wv * 32 + c * 16 + col16;
      float bj = m.bias ? m.bias[col] : 0.f;
#pragma unroll
      for (int g = 0; g < 4; g++)
        sA[(rt * 16 + quad * 4 + g) * ESTRIDE + col] = f2bf(acc[rt * 2 + c][g] + bj);
    }
  __syncthreads();
  {
    int rr = tid / TPR, d = tid % TPR;
    int rowg = r0 + rr;
    if (rowg < NN) {
      const u16* sp2 = sA + rr * ESTRIDE + d * 64;
      uint4* o = (uint4*)(m.out + (long)rowg * 128 + d * 64);
#pragma unroll
      for (int e = 0; e < 8; e++) {
        const uint2* s2 = (const uint2*)(sp2 + e * 8);
        uint2 lo = s2[0], hi = s2[1];
        o[e] = make_uint4(lo.x, lo.y, hi.x, hi.y);
      }
    }
  }
  if (m.part) {
    __shared__ float ps[256], pq[256];
    int col = tid & 127, hf = tid >> 7;
    float s = 0.f, q = 0.f;
#pragma unroll
    for (int r = 0; r < 64; r++) {
      int rr = hf * 64 + r;
      if (r0 + rr < NN) {
        float v = bf2f(sA[rr * ESTRIDE + col]);
        s += v;
        q += v * v;
      }
    }
    ps[tid] = s;
    pq[tid] = q;
    __syncthreads();
    if (tid < 128) {
      m.part[(long)blockIdx.x * 256 + tid] = ps[tid] + ps[tid + 128];
      m.part[(long)blockIdx.x * 256 + 128 + tid] = pq[tid] + pq[tid + 128];
    }
  }
}

// ------------- fused: S-gather + ET GEMM + mean + preprocess GEMM -------------
__global__ __launch_bounds__(256) void k_etpre(const u16* __restrict__ Xg,
                                               const u16* __restrict__ asum,
                                               const u16* __restrict__ Wet,
                                               const u16* __restrict__ Wpre,
                                               const float* __restrict__ b_int,
                                               const float* __restrict__ b_pre,
                                               const int* __restrict__ off,
                                               const int* __restrict__ crow,
                                               u16* __restrict__ out, float* part) {
  __shared__ __align__(16) u16 sA[64 * ASTRIDE];
  __shared__ __align__(16) u16 sE[64 * 32];
  int tid = threadIdx.x;
  int wv = tid >> 6, lane = tid & 63;
  int col16 = lane & 15, quad = lane >> 4;
  int r0 = blockIdx.x * 64;

  gather_lds<0>(sA, Xg, off, crow, nullptr, r0);
  {
    int row = tid >> 2, seg = tid & 3;
    int ra = r0 + row;
    if (ra >= NN) ra = NN - 1;
    if (seg < 2)
      *(uint4*)(sE + row * 32 + seg * 8) = *(const uint4*)(asum + (long)ra * 16 + seg * 8);
    else
      *(uint4*)(sE + row * 32 + seg * 8) = make_uint4(0, 0, 0, 0);
  }
  bfrag be[2];
#pragma unroll
  for (int c = 0; c < 2; c++)
    be[c] = *(const bfrag*)(Wet + (long)(wv * 32 + c * 16 + col16) * 32 + quad * 8);
  __syncthreads();
  ffrag accE[8];
#pragma unroll
  for (int i = 0; i < 8; i++)
#pragma unroll
    for (int g = 0; g < 4; g++) accE[i][g] = 0.f;
#pragma unroll
  for (int rt = 0; rt < 4; rt++) {
    bfrag af = *(const bfrag*)(sE + (rt * 16 + col16) * 32 + quad * 8);
    accE[rt * 2 + 0] = __builtin_amdgcn_mfma_f32_16x16x32_bf16(af, be[0], accE[rt * 2 + 0], 0, 0, 0);
    accE[rt * 2 + 1] = __builtin_amdgcn_mfma_f32_16x16x32_bf16(af, be[1], accE[rt * 2 + 1], 0, 0, 0);
  }
#pragma unroll
  for (int rt = 0; rt < 4; rt++)
#pragma unroll
    for (int g = 0; g < 4; g++) {
      int rr = rt * 16 + quad * 4 + g;
      int r = r0 + rr;
      int cc = (r < NN) ? off[r + 1] - off[r] : 0;
      float inv = 1.f / (float)(cc > 1 ? cc : 1);
#pragma unroll
      for (int c = 0; c < 2; c++) {
        int col = wv * 32 + c * 16 + col16;
        float bj = b_int[col];
        float v = accE[rt * 2 + c][g] + bf2f(sA[rr * ASTRIDE + col]);
        v = (v + (float)cc * bj) * inv;
        sA[rr * ASTRIDE + col] = f2bf(v);
      }
    }
  bfrag b1[2][4];
#pragma unroll
  for (int c = 0; c < 2; c++)
#pragma unroll
    for (int kb = 0; kb < 4; kb++)
      b1[c][kb] = *(const bfrag*)(Wpre + (long)(wv * 32 + c * 16 + col16) * 128 + kb * 32 + quad * 8);
  __syncthreads();
  ffrag a2[8];
#pragma unroll
  for (int i = 0; i < 8; i++)
#pragma unroll
    for (int g = 0; g < 4; g++) a2[i][g] = 0.f;
#pragma unroll
  for (int kb = 0; kb < 4; kb++)
#pragma unroll
    for (int rt = 0; rt < 4; rt++) {
      bfrag af = *(const bfrag*)(sA + (rt * 16 + col16) * ASTRIDE + kb * 32 + quad * 8);
      a2[rt * 2 + 0] = __builtin_amdgcn_mfma_f32_16x16x32_bf16(af, b1[0][kb], a2[rt * 2 + 0], 0, 0, 0);
      a2[rt * 2 + 1] = __builtin_amdgcn_mfma_f32_16x16x32_bf16(af, b1[1][kb], a2[rt * 2 + 1], 0, 0, 0);
    }
  __syncthreads();
#pragma unroll
  for (int rt = 0; rt < 4; rt++)
#pragma unroll
    for (int c = 0; c < 2; c++) {
      int col = wv * 32 + c * 16 + col16;
      float bj = b_pre[col];
#pragma unroll
      for (int g = 0; g < 4; g++)
        sA[(rt * 16 + quad * 4 + g) * ESTRIDE + col] = f2bf(a2[rt * 2 + c][g] + bj);
    }
  __syncthreads();
  {
    int rr = tid >> 2, d = tid & 3;
    int rowg = r0 + rr;
    if (rowg < NN) {
      const u16* sp2 = sA + rr * ESTRIDE + d * 32;
      uint4* o = (uint4*)(out + (long)rowg * 128 + d * 32);
#pragma unroll
      for (int e = 0; e < 4; e++) {
        const uint2* s2 = (const uint2*)(sp2 + e * 8);
        uint2 lo = s2[0], hi = s2[1];
        o[e] = make_uint4(lo.x, lo.y, hi.x, hi.y);
      }
    }
  }
  {
    __shared__ float ps[256], pq[256];
    int col = tid & 127, hf = tid >> 7;
    float s = 0.f, q = 0.f;
#pragma unroll
    for (int r = 0; r < 32; r++) {
      int rr = hf * 32 + r;
      if (r0 + rr < NN) {
        float v = bf2f(sA[rr * ESTRIDE + col]);
        s += v;
        q += v * v;
      }
    }
    ps[tid] = s;
    pq[tid] = q;
    __syncthreads();
    if (tid < 128) {
      part[(long)blockIdx.x * 256 + tid] = ps[tid] + ps[tid + 128];
      part[(long)blockIdx.x * 256 + 128 + tid] = pq[tid] + pq[tid + 128];
    }
  }
}

// ------------- fused cheb layer: out = relu(BN?(hb)@WD + T1@W1 + L(T1)@V2 + b) -------------
// merged rounds: {gather L(T1)->sA, stage hb->sB} sync {MFMA V2, MFMA WD} sync
//                {stage T1->sA} sync {MFMA W1} sync epilogue
template <int BN>
__global__ __launch_bounds__(256) void k_cheb(const u16* __restrict__ hb,
                                              const u16* __restrict__ T1,
                                              const int* __restrict__ off,
                                              const int* __restrict__ crow,
                                              const float* __restrict__ cnorm,
                                              const u16* __restrict__ WD,
                                              const u16* __restrict__ W1,
                                              const u16* __restrict__ V2,
                                              const float* __restrict__ bias,
                                              const float* __restrict__ ab,
                                              u16* __restrict__ out) {
  __shared__ __align__(16) u16 sA[64 * ASTRIDE];
  __shared__ __align__(16) u16 sB[64 * ASTRIDE];
  int tid = threadIdx.x;
  int wv = tid >> 6, lane = tid & 63;
  int col16 = lane & 15, quad = lane >> 4;
  int r0 = blockIdx.x * 64;

  // gather L(T1) -> sA (heavy) ; stage hb -> sB (streams overlap via other waves)
  gather_lds<1>(sA, T1, off, crow, cnorm, r0);
  {
    int row = tid >> 2, seg = tid & 3;
    int ra = r0 + row;
    if (ra >= NN) ra = NN - 1;
    const u16* gs = hb + (long)ra * 128 + seg * 32;
    uint4* lp = (uint4*)(sB + row * ASTRIDE + seg * 32);
    if (BN) {
#pragma unroll
      for (int e = 0; e < 4; e++) {
        uint4 v = *(const uint4*)(gs + e * 8);
        int cb = seg * 32 + e * 8;
        float f0 = fmaxf(fmaf(ab[cb + 0], __uint_as_float(v.x << 16), ab[128 + cb + 0]), 0.f);
        float f1 = fmaxf(fmaf(ab[cb + 1], __uint_as_float(v.x & 0xffff0000u), ab[128 + cb + 1]), 0.f);
        float f2 = fmaxf(fmaf(ab[cb + 2], __uint_as_float(v.y << 16), ab[128 + cb + 2]), 0.f);
        float f3 = fmaxf(fmaf(ab[cb + 3], __uint_as_float(v.y & 0xffff0000u), ab[128 + cb + 3]), 0.f);
        float f4 = fmaxf(fmaf(ab[cb + 4], __uint_as_float(v.z << 16), ab[128 + cb + 4]), 0.f);
        float f5 = fmaxf(fmaf(ab[cb + 5], __uint_as_float(v.z & 0xffff0000u), ab[128 + cb + 5]), 0.f);
        float f6 = fmaxf(fmaf(ab[cb + 6], __uint_as_float(v.w << 16), ab[128 + cb + 6]), 0.f);
        float f7 = fmaxf(fmaf(ab[cb + 7], __uint_as_float(v.w & 0xffff0000u), ab[128 + cb + 7]), 0.f);
        uint4 o;
        o.x = (u32)f2bf(f0) | ((u32)f2bf(f1) << 16);
        o.y = (u32)f2bf(f2) | ((u32)f2bf(f3) << 16);
        o.z = (u32)f2bf(f4) | ((u32)f2bf(f5) << 16);
        o.w = (u32)f2bf(f6) | ((u32)f2bf(f7) << 16);
        lp[e] = o;
      }
    } else {
#pragma unroll
      for (int e = 0; e < 4; e++) lp[e] = *(const uint4*)(gs + e * 8);
    }
  }
  bfrag bv[2][4];
#pragma unroll
  for (int c = 0; c < 2; c++)
#pragma unroll
    for (int kb = 0; kb < 4; kb++)
      bv[c][kb] = *(const bfrag*)(V2 + (long)(wv * 32 + c * 16 + col16) * 128 + kb * 32 + quad * 8);
  __syncthreads();
  ffrag acc[8];
#pragma unroll
  for (int i = 0; i < 8; i++)
#pragma unroll
    for (int g = 0; g < 4; g++) acc[i][g] = 0.f;
  // MFMA with V2 from sA
#pragma unroll
  for (int kb = 0; kb < 4; kb++)
#pragma unroll
    for (int rt = 0; rt < 4; rt++) {
      bfrag af = *(const bfrag*)(sA + (rt * 16 + col16) * ASTRIDE + kb * 32 + quad * 8);
      acc[rt * 2 + 0] = __builtin_amdgcn_mfma_f32_16x16x32_bf16(af, bv[0][kb], acc[rt * 2 + 0], 0, 0, 0);
      acc[rt * 2 + 1] = __builtin_amdgcn_mfma_f32_16x16x32_bf16(af, bv[1][kb], acc[rt * 2 + 1], 0, 0, 0);
    }
  // MFMA with WD from sB (reload frags, same registers)
#pragma unroll
  for (int c = 0; c < 2; c++)
#pragma unroll
    for (int kb = 0; kb < 4; kb++)
      bv[c][kb] = *(const bfrag*)(WD + (long)(wv * 32 + c * 16 + col16) * 128 + kb * 32 + quad * 8);
#pragma unroll
  for (int kb = 0; kb < 4; kb++)
#pragma unroll
    for (int rt = 0; rt < 4; rt++) {
      bfrag af = *(const bfrag*)(sB + (rt * 16 + col16) * ASTRIDE + kb * 32 + quad * 8);
      acc[rt * 2 + 0] = __builtin_amdgcn_mfma_f32_16x16x32_bf16(af, bv[0][kb], acc[rt * 2 + 0], 0, 0, 0);
      acc[rt * 2 + 1] = __builtin_amdgcn_mfma_f32_16x16x32_bf16(af, bv[1][kb], acc[rt * 2 + 1], 0, 0, 0);
    }
  __syncthreads();

  // stage T1 own rows -> sA ; MFMA with W1
  {
    int row = tid >> 2, seg = tid & 3;
    int ra = r0 + row;
    if (ra >= NN) ra = NN - 1;
    const u16* gs = T1 + (long)ra * 128 + seg * 32;
    uint4* lp = (uint4*)(sA + row * ASTRIDE + seg * 32);
#pragma unroll
    for (int e = 0; e < 4; e++) lp[e] = *(const uint4*)(gs + e * 8);
  }
#pragma unroll
  for (int c = 0; c < 2; c++)
#pragma unroll
    for (int kb = 0; kb < 4; kb++)
      bv[c][kb] = *(const bfrag*)(W1 + (long)(wv * 32 + c * 16 + col16) * 128 + kb * 32 + quad * 8);
  __syncthreads();
#pragma unroll
  for (int kb = 0; kb < 4; kb++)
#pragma unroll
    for (int rt = 0; rt < 4; rt++) {
      bfrag af = *(const bfrag*)(sA + (rt * 16 + col16) * ASTRIDE + kb * 32 + quad * 8);
      acc[rt * 2 + 0] = __builtin_amdgcn_mfma_f32_16x16x32_bf16(af, bv[0][kb], acc[rt * 2 + 0], 0, 0, 0);
      acc[rt * 2 + 1] = __builtin_amdgcn_mfma_f32_16x16x32_bf16(af, bv[1][kb], acc[rt * 2 + 1], 0, 0, 0);
    }
  __syncthreads();

  // epilogue: +bias, relu, repack, store
#pragma unroll
  for (int rt = 0; rt < 4; rt++)
#pragma unroll
    for (int c = 0; c < 2; c++) {
      int col = wv * 32 + c * 16 + col16;
      float bj = bias[col];
#pragma unroll
      for (int g = 0; g < 4; g++)
        sA[(rt * 16 + quad * 4 + g) * ESTRIDE + col] = f2bf(fmaxf(acc[rt * 2 + c][g] + bj, 0.f));
    }
  __syncthreads();
  {
    int rr = tid >> 2, d = tid & 3;
    int rowg = r0 + rr;
    if (rowg < NN) {
      const u16* sp2 = sA + rr * ESTRIDE + d * 32;
      uint4* o = (uint4*)(out + (long)rowg * 128 + d * 32);
#pragma unroll
      for (int e = 0; e < 4; e++) {
        const uint2* s2 = (const uint2*)(sp2 + e * 8);
        uint2 lo = s2[0], hi = s2[1];
        o[e] = make_uint4(lo.x, lo.y, hi.x, hi.y);
      }
    }
  }
}

// ------------- reduce partials + BN finalize fused -------------
__global__ void k_redfin(const float* __restrict__ part, const float* __restrict__ gamma,
                         const float* __restrict__ beta, float* ab, int nblk) {
  int tid = threadIdx.x;
  int col = blockIdx.x * 16 + (tid & 15);
  int ch = tid >> 4;
  float s = 0.f, q = 0.f;
  for (int b = ch; b < nblk; b += 16) {
    s += part[(long)b * 256 + col];
    q += part[(long)b * 256 + 128 + col];
  }
  __shared__ float sh[256], qh[256];
  sh[tid] = s;
  qh[tid] = q;
  __syncthreads();
  if (tid < 16) {
    float ts = 0.f, tq = 0.f;
#pragma unroll
    for (int i = 0; i < 16; i++) {
      ts += sh[i * 16 + tid];
      tq += qh[i * 16 + tid];
    }
    int j = blockIdx.x * 16 + tid;
    float m = ts * (1.f / (float)NN);
    float v = fmaxf(tq * (1.f / (float)NN) - m * m, 0.f);
    float a = gamma[j] * rsqrtf(v + 1e-5f);
    ab[j] = a;
    ab[128 + j] = beta[j] - m * a;
  }
}

__global__ void k_out(const u16* __restrict__ z, const float* __restrict__ ab,
                      const float* __restrict__ wout, const float* __restrict__ bout,
                      const u32* __restrict__ gp, void* __restrict__ y) {
  int node = blockIdx.x * 4 + (threadIdx.x >> 6);
  if (node >= NN) return;
  int lane = threadIdx.x & 63;
  float s = 0.f;
#pragma unroll
  for (int c = lane; c < 128; c += 64) {
    float zz = bf2f(z[(long)node * 128 + c]);
    float h = fmaxf(ab[c] * zz + ab[128 + c], 0.f);
    s += h * wout[c];
  }
#pragma unroll
  for (int o = 32; o > 0; o >>= 1) s += __shfl_down(s, o);
  if (lane == 0) {
    float r = s + bout[0];
    if (gp[0] == BF16ONE2) ((u16*)y)[node] = f2bf(r);
    else ((float*)y)[node] = r;
  }
}

extern "C" void kernel_launch(void* const* d_in, const int* in_sizes, int n_in,
                              void* d_out, int out_size, void* d_ws, size_t ws_size,
                              hipStream_t stream) {
  const void* x = d_in[0];
  const int* ei = (const int*)d_in[1];
  const void* eattr = d_in[2];
  const u32* gp = (const u32*)d_in[7];
  (void)in_sizes; (void)n_in; (void)out_size; (void)ws_size;

  char* w = (char*)d_ws;
  size_t p = 0;
  auto alloc = [&](size_t b) { size_t r = p; p += (b + 255) & ~(size_t)255; return r; };
  size_t o_deg = alloc((size_t)NN * 4);
  size_t o_off = alloc((size_t)(NN + 1) * 4);
  size_t o_bcnt = alloc((size_t)NBKT * NBLK * 4);
  size_t o_rbcnt = alloc((size_t)NBKT * NBLK * 4);
  size_t o_btot = alloc((size_t)2 * NBKT * 4);
  size_t o_bbase = alloc((size_t)(NBKT + 1) * 4);
  size_t o_rbbase = alloc((size_t)(NBKT + 1) * 4);
  size_t o_ab = alloc(512 * 4);
  size_t o_wq = alloc((size_t)151552 * 2);
  size_t o_wf = alloc((size_t)1281 * 4);
  size_t o_crow = alloc((size_t)NE * 4);
  size_t o_cnrm = alloc((size_t)NE * 4);
  size_t o_asum = alloc((size_t)NN * 16 * 2);
  size_t o_part = alloc((size_t)1563 * 256 * 4);
  size_t o_Bx = alloc((size_t)NN * 128 * 2);
  size_t o_eac = alloc((size_t)NE * 16 * 2);  // 32 MB; Bt aliases head (25.6 MB)

  int* deg = (int*)(w + o_deg);
  int* off = (int*)(w + o_off);
  int* bcnt = (int*)(w + o_bcnt);
  int* rbcnt = (int*)(w + o_rbcnt);
  int* btot = (int*)(w + o_btot);
  int* bbase = (int*)(w + o_bbase);
  int* rbbase = (int*)(w + o_rbbase);
  float* abA = (float*)(w + o_ab);
  float* abB = abA + 256;
  u16* wq = (u16*)(w + o_wq);
  float* wf = (float*)(w + o_wf);
  int* crow = (int*)(w + o_crow);
  float* cnrm = (float*)(w + o_cnrm);
  u16* asum = (u16*)(w + o_asum);
  float* part = (float*)(w + o_part);
  u16* Bx = (u16*)(w + o_Bx);
  u16* eac = (u16*)(w + o_eac);
  u16* Bt = eac;  // alias: eatt_csr dead after k_asum, before Bt first written
  // build-time overlays:
  u32* sle = (u32*)Bx;           // 4 MB  (dead after k_fine)
  u32* srow = sle + NE;          // 4 MB  (dead after k_fine)
  u16* srl = (u16*)(srow + NE);  // 2 MB  (dead after k_deg)
  int* pose = (int*)cnrm;        // 4 MB  (dead after k_escat; cnrm written later by k_asum)

  int gS = (NN + 7) / 8;
  int gN16 = (NN * 16 + 255) / 256;
  int gE4 = (int)((NE / 4 + 255) / 256) + 1;
  int gG1 = (NN + 127) / 128;  // 782
  int gG2 = (NN + 63) / 64;    // 1563

  {
    PrepArgs a;
    for (int i = 0; i < 16; i++) a.in[i] = d_in[3 + i];
    k_prep<<<64, 256, 0, stream>>>(a, gp, wq, wf);
  }

  // ---- CSR build: LDS two-level counting sort
  k_cnt<<<NBLK, 256, 0, stream>>>(ei, bcnt, rbcnt);
  k_bscan<<<2 * NBKT, 256, 0, stream>>>(bcnt, rbcnt, btot);
  k_bbase<<<1, 256, 0, stream>>>(btot, bbase, rbbase, off);
  k_scat<<<NBLK, 256, 0, stream>>>(ei, bcnt, rbcnt, bbase, rbbase, sle, srow, srl);
  k_fine<<<NBKT, 256, 0, stream>>>(sle, srow, bbase, off, crow, pose);
  k_deg<<<NBKT, 256, 0, stream>>>(srl, rbbase, deg);

  // ---- eattr -> CSR order (coalesced read, scatter write), then coalesced segsum
  k_escat<<<gE4, 256, 0, stream>>>(eattr, gp, pose, eac);
  k_asum<<<gN16, 256, 0, stream>>>(eac, asum, off, crow, deg, cnrm);

  // ---- Xg = x @ Wx -> Bx
  {
    MArgs a = {};
    a.A0 = x; a.W0T = wq + OWXT; a.a0raw = 1;
    a.out = Bx; a.gp = gp;
    k_mgemm<<<gG1, 256, 0, stream>>>(a);
  }
  // ---- fused: S = segsum(Xg), h = (S+asum@We+cnt*b)/cnt, z = h@Wpre+b -> Bt
  k_etpre<<<gG2, 256, 0, stream>>>(Bx, asum, wq + OWET, wq + OWPRE, wf + 0, wf + 128,
                                   off, crow, Bt, part);
  k_redfin<<<8, 256, 0, stream>>>(part, wf + 256, wf + 384, abA, gG2);

  // ---- cheb1 (BN fused into consumers)
  k_spmm<1><<<gS, 256, 0, stream>>>(Bt, Bx, off, crow, cnrm, abA);
  k_cheb<1><<<gG2, 256, 0, stream>>>(Bt, Bx, off, crow, cnrm,
                                     wq + OWD1, wq + OW11, wq + OV21, wf + 512, abA, Bt);

  // ---- cheb2 (plain)
  k_spmm<0><<<gS, 256, 0, stream>>>(Bt, Bx, off, crow, cnrm, nullptr);
  k_cheb<0><<<gG2, 256, 0, stream>>>(Bt, Bx, off, crow, cnrm,
                                     wq + OWD2, wq + OW12, wq + OV22, wf + 640, nullptr, Bt);

  // ---- postprocess: z2 = h3@Wpost + b -> Bx (+partials) ; BN+relu+dot -> y
  {
    MArgs a = {};
    a.A0 = Bt; a.W0T = wq + OWPOST;
    a.bias = wf + 768; a.out = Bx; a.gp = gp; a.part = part;
    k_mgemm<<<gG1, 256, 0, stream>>>(a);
  }
  k_redfin<<<8, 256, 0, stream>>>(part, wf + 896, wf + 1024, abB, gG1);
  k_out<<<(NN + 3) / 4, 256, 0, stream>>>(Bx, abB, wf + 1152, wf + 1280, gp, d_out);
}